// Round 13
// baseline (55.658 us; speedup 1.0000x reference)
//
#include <hip/hip_runtime.h>

#define HH 64
#define WW 64
#define TT 16
#define NPIX (HH * WW * TT)   // 65536
#define HALO 10               // 4 + 2*3
#define HWH  (HALO * HALO)    // 100 halo (h,w) positions
#define TPAD 20               // padded t-stride (16 data + 4 pad) -> bank-conflict-free
#define CH_STRIDE (HWH * TPAD)   // 2000 floats per channel
#define NCH 18                // gui(9) + est(3) + var(3) + img(3) ALL staged

// lane i <- lane i-1 within 16-lane DPP rows (row_shr:1), 0-fill at row start.
__device__ __forceinline__ float dpp_up1(float x) {
    return __int_as_float(__builtin_amdgcn_update_dpp(
        0, __float_as_int(x), 0x111, 0xF, 0xF, true));
}
// lane i <- lane i+1 within 16-lane DPP rows (row_shl:1), 0-fill at row end.
__device__ __forceinline__ float dpp_dn1(float x) {
    return __int_as_float(__builtin_amdgcn_update_dpp(
        0, __float_as_int(x), 0x101, 0xF, 0xF, true));
}

// R12 structure + two measured fixes:
//  (1) LDS t-stride 16 -> 20 floats: addr = row*20 + tg*4; 20*row mod 32
//      cycles period-8 -> wave's 16 rows spread all 32 banks (~2-way, free)
//      vs 16*row mod 32 = 16*(row&1) -> 8-way (R12's 2.68M conflicts).
//  (2) 1024 threads with EXPLICIT __launch_bounds__(1024, 4): VGPR cap 512
//      (R11's spill was the default cap=64, not the width) -> 16 waves =
//      4 waves/SIMD, 16 column-splits.
// 256 blocks (1/CU, LDS-enforced at 144 KB). Tile 4x4x16, halo 10x10x16,
// all 18 channels staged -> K-loop pure LDS+VALU, no barriers. K=4
// t-blocking: lane = hw*4+tg, owns t={4tg..4tg+3} (float4 + DPP t-halo;
// DPP garbage only at tg=0/tg=3, exactly the OOB-masked pairs).
__global__ __launch_bounds__(1024, 4) void statdenoise_kernel(
    const float* __restrict__ img,
    const float* __restrict__ gui,
    const float* __restrict__ est,
    const float* __restrict__ var,
    float* __restrict__ out)
{
    __shared__ float smem[NCH * CH_STRIDE];   // 144 KB; aliased by reduction later

    const float SIG[9] = {0.1f, 0.1f, 0.1f, 50.0f, 50.0f, 50.0f, 10.0f, 10.0f, 10.0f};
    const float G2 = 2.907f * 2.907f;   // gamma^2

    const int tid  = threadIdx.x;
    const int lane = tid & 63;
    const int s    = tid >> 6;      // wave id == column-split 0..15
    const int tg   = lane & 3;      // t-group 0..3
    const int hwl  = lane >> 2;     // tile pixel 0..15
    const int t0   = tg * 4;        // owns t0..t0+3
    const int h0   = (blockIdx.x >> 4) << 2;   // 16x16 tiles of 4x4
    const int w0   = (blockIdx.x & 15) << 2;

    // ---- stage all 18 channels of the 10x10x16 halo (edge-clamped; OOB
    //      pairs masked later by inb, same semantics as clamped loads) ----
#pragma unroll
    for (int rep = 0; rep < 2; ++rep) {
        const int q = tid + rep * 1024;
        if (q < HWH * TT) {
            const int t   = q & 15;
            const int hwq = q >> 4;                  // 0..99
            const int hq  = (hwq * 205) >> 11;       // exact /10 for hwq<1024
            const int wq  = hwq - hq * 10;
            const int hs  = min(max(h0 - 3 + hq, 0), HH - 1);
            const int ws  = min(max(w0 - 3 + wq, 0), WW - 1);
            const int g   = (((hs << 6) + ws) << 4) + t;
            const int p   = hwq * TPAD + t;          // padded LDS address
#pragma unroll
            for (int c = 0; c < 9; ++c) smem[c * CH_STRIDE + p] = gui[c * NPIX + g];
#pragma unroll
            for (int c = 0; c < 3; ++c) {
                smem[(9 + c)  * CH_STRIDE + p] = est[c * NPIX + g];
                smem[(12 + c) * CH_STRIDE + p] = var[c * NPIX + g];
                smem[(15 + c) * CH_STRIDE + p] = img[c * NPIX + g];
            }
        }
    }
    __syncthreads();

    const int th = hwl >> 2, tw = hwl & 3;     // tile-local pixel
    const int hg = h0 + th,  wg = w0 + tw;     // global pixel

    // center values from LDS (float4 along t)
    const int rowc = (th + 3) * 10 + (tw + 3);
    const int lc = rowc * TPAD + t0;
    float4 gc[9];
#pragma unroll
    for (int c = 0; c < 9; ++c) gc[c] = *(const float4*)&smem[c * CH_STRIDE + lc];
    float4 ec[3], vc[3];
#pragma unroll
    for (int c = 0; c < 3; ++c) {
        ec[c] = *(const float4*)&smem[(9 + c)  * CH_STRIDE + lc];
        vc[c] = *(const float4*)&smem[(12 + c) * CH_STRIDE + lc];
    }

    const bool vLo = (t0 != 0);     // pair (e=0,k=0): t0-1  (also DPP garbage mask)
    const bool vHi = (t0 != 12);    // pair (e=3,k=2): t0+4  (also DPP garbage mask)

    float acc[4][4] = {};   // per owned t: {r,g,b,wsum}

    int dh = s / 7 - 3, dw = s % 7 - 3;   // column r = s, then += 16
    for (int r = s; r < 49; r += 16) {
        // halo coords always in range: th+dh+3 in [0,9], tw+dw+3 in [0,9]
        const int lb  = (rowc + dh * 10 + dw) * TPAD + t0;
        const bool inb = ((unsigned)(hg + dh) < (unsigned)HH) &
                         ((unsigned)(wg + dw) < (unsigned)WW);

        // ---- bilateral over 9 guidance channels, 12 (e,dt) pairs ----
        float sb[4][3] = {};
#pragma unroll
        for (int c = 0; c < 9; ++c) {
            float4 m = *(const float4*)&smem[c * CH_STRIDE + lb];
            float nv[6] = {dpp_up1(m.w), m.x, m.y, m.z, m.w, dpp_dn1(m.x)};
            float ce[4] = {gc[c].x, gc[c].y, gc[c].z, gc[c].w};
#pragma unroll
            for (int e = 0; e < 4; ++e) {
#pragma unroll
                for (int k = 0; k < 3; ++k) {        // neighbor t = t0+e+k-1
                    float d = ce[e] - nv[e + k];
                    sb[e][k] = fmaf(d * d, SIG[c], sb[e][k]);
                }
            }
        }

        // ---- membership (division-free Welch t-test) ----
        // (OOB h/w neighbors provably get weight 0 in the reference -> inb;
        //  center pair passes naturally: d2==0.)
        bool mem[4][3] = {{1,1,1},{1,1,1},{1,1,1},{1,1,1}};
#pragma unroll
        for (int c = 0; c < 3; ++c) {
            float4 em = *(const float4*)&smem[(9 + c)  * CH_STRIDE + lb];
            float4 vm = *(const float4*)&smem[(12 + c) * CH_STRIDE + lb];
            float env[6] = {dpp_up1(em.w), em.x, em.y, em.z, em.w, dpp_dn1(em.x)};
            float vnv[6] = {dpp_up1(vm.w), vm.x, vm.y, vm.z, vm.w, dpp_dn1(vm.x)};
            float ece[4] = {ec[c].x, ec[c].y, ec[c].z, ec[c].w};
            float vce[4] = {vc[c].x, vc[c].y, vc[c].z, vc[c].w};
#pragma unroll
            for (int e = 0; e < 4; ++e) {
#pragma unroll
                for (int k = 0; k < 3; ++k) {
                    float d  = ece[e] - env[e + k];
                    float d2 = d * d;
                    float V  = vce[e] + vnv[e + k];
                    bool pass = (d2 < G2 * V) | ((d2 == 0.f) & (V == 0.f));
                    bool kill = ((vce[e] == 0.f) | (vnv[e + k] == 0.f)) & (d2 != 0.f);
                    mem[e][k] = mem[e][k] & pass & (!kill);
                }
            }
        }

        // ---- weights ----
        float wt[4][3];
#pragma unroll
        for (int e = 0; e < 4; ++e) {
#pragma unroll
            for (int k = 0; k < 3; ++k) {
                bool ok = inb && mem[e][k];
                if (e == 0 && k == 0) ok = ok && vLo;   // t0-1
                if (e == 3 && k == 2) ok = ok && vHi;   // t0+4
                wt[e][k] = ok ? __expf(-0.5f * sb[e][k]) : 0.f;
            }
        }

        // ---- accumulate image (from LDS) ----
#pragma unroll
        for (int c = 0; c < 3; ++c) {
            float4 im = *(const float4*)&smem[(15 + c) * CH_STRIDE + lb];
            float iv[6] = {dpp_up1(im.w), im.x, im.y, im.z, im.w, dpp_dn1(im.x)};
#pragma unroll
            for (int e = 0; e < 4; ++e) {
                acc[e][c] = fmaf(wt[e][0], iv[e],
                            fmaf(wt[e][1], iv[e + 1],
                            fmaf(wt[e][2], iv[e + 2], acc[e][c])));
            }
        }
#pragma unroll
        for (int e = 0; e < 4; ++e)
            acc[e][3] += wt[e][0] + wt[e][1] + wt[e][2];

        dw += 16;
        while (dw > 3) { dw -= 7; ++dh; }
    }

    // ---- combine the 16 splits (alias staging LDS after all reads done) ----
    __syncthreads();
    float4* red = (float4*)smem;          // 16*64*4 float4 = 64 KB < 144 KB
#pragma unroll
    for (int e = 0; e < 4; ++e)
        red[(s * 64 + lane) * 4 + e] = make_float4(acc[e][0], acc[e][1], acc[e][2], acc[e][3]);
    __syncthreads();

    if (tid < 256) {
        const int hw_ = tid >> 4;           // tile pixel 0..15
        const int t_  = tid & 15;           // t 0..15
        const int tg_ = t_ >> 2, e_ = t_ & 3;
        const int li  = hw_ * 4 + tg_;      // lane that owns this (hw, t0) group
        float4 sum = make_float4(0.f, 0.f, 0.f, 0.f);
#pragma unroll
        for (int q = 0; q < 16; ++q) {
            float4 v = red[(q * 64 + li) * 4 + e_];
            sum.x += v.x; sum.y += v.y; sum.z += v.z; sum.w += v.w;
        }
        const int th_ = hw_ >> 2, tw_ = hw_ & 3;
        const int px = ((((h0 + th_) << 6) + (w0 + tw_)) << 4) + t_;
        const float inv = 1.f / sum.w;      // wsum >= 1 (center weight == 1)
        out[0 * NPIX + px] = sum.x * inv;
        out[1 * NPIX + px] = sum.y * inv;
        out[2 * NPIX + px] = sum.z * inv;
    }
}

extern "C" void kernel_launch(void* const* d_in, const int* in_sizes, int n_in,
                              void* d_out, int out_size, void* d_ws, size_t ws_size,
                              hipStream_t stream) {
    const float* img = (const float*)d_in[0];
    const float* gui = (const float*)d_in[1];
    const float* est = (const float*)d_in[2];
    const float* var = (const float*)d_in[3];
    float* out = (float*)d_out;

    dim3 grid(256);     // 16x16 tiles of 4x4x16, 1 block per CU (LDS-enforced)
    dim3 block(1024);   // 16 waves = 16 column-splits; wave covers whole tile
    statdenoise_kernel<<<grid, block, 0, stream>>>(img, gui, est, var, out);
}

// Round 14
// 42.471 us; speedup vs baseline: 1.3105x; 1.3105x over previous
//
#include <hip/hip_runtime.h>

#define HH 64
#define WW 64
#define TT 16
#define NPIX (HH * WW * TT)   // 65536
#define HALO 10               // 4 + 2*3
#define HWH  (HALO * HALO)    // 100 halo (h,w) positions
#define CH_SZ (HWH * TT)      // 1600 floats per channel (NO pad; XOR swizzle)
#define NCH 18                // gui(9) + est(3) + var(3) + img(3) ALL staged

// Bank swizzle: element (row, t) lives at row*16 + (t ^ ((row&6)<<1)).
// XOR acts on the float4-slot bits (2-3) only -> each b128 read stays 16
// consecutive bytes; bank-group (4*row + slot^((row>>1)&3)) mod 8 covers
// all 8 groups across row mod 8 -> 2 lanes/group for a wave's 16 rows
// (2-way = free, m136) vs unswizzled 8-way (R12's 2.68M conflict cycles).
#define SWZ(row, t) (((row) << 4) + ((t) ^ (((row) & 6) << 1)))

// lane i <- lane i-1 within 16-lane DPP rows (row_shr:1), 0-fill at row start.
__device__ __forceinline__ float dpp_up1(float x) {
    return __int_as_float(__builtin_amdgcn_update_dpp(
        0, __float_as_int(x), 0x111, 0xF, 0xF, true));
}
// lane i <- lane i+1 within 16-lane DPP rows (row_shl:1), 0-fill at row end.
__device__ __forceinline__ float dpp_dn1(float x) {
    return __int_as_float(__builtin_amdgcn_update_dpp(
        0, __float_as_int(x), 0x101, 0xF, 0xF, true));
}

// R12 structure (512 thr -> VGPR 96, no spill; 1024 thr proven dead twice:
// hipcc caps VGPR at 64 -> 100MB spill) + XOR bank swizzle (zero LDS cost)
// + sqrt(sigma)-prescaled bilateral + hoisted vc==0 compares.
// 256 blocks (1/CU, LDS-enforced at 115.2 KB). Tile 4x4x16, halo 10x10x16,
// all 18 channels staged -> K-loop pure LDS+VALU, no barriers. K=4
// t-blocking: lane = hw*4+tg, owns t={4tg..4tg+3} (float4 + DPP t-halo;
// DPP garbage only at tg=0/tg=3, exactly the OOB-masked pairs).
__global__ __launch_bounds__(512, 2) void statdenoise_kernel(
    const float* __restrict__ img,
    const float* __restrict__ gui,
    const float* __restrict__ est,
    const float* __restrict__ var,
    float* __restrict__ out)
{
    __shared__ float smem[NCH * CH_SZ];   // 115.2 KB; aliased by reduction later

    // sqrt(SIG): bilateral uses (sqrt(s)*a - sqrt(s)*b)^2 == s*(a-b)^2 (+~1e-7 rel)
    const float SQS[9] = {0.3162277660f, 0.3162277660f, 0.3162277660f,
                          7.0710678119f, 7.0710678119f, 7.0710678119f,
                          3.1622776602f, 3.1622776602f, 3.1622776602f};
    const float G2 = 2.907f * 2.907f;   // gamma^2

    const int tid  = threadIdx.x;
    const int lane = tid & 63;
    const int s    = tid >> 6;      // wave id == column-split 0..7
    const int tg   = lane & 3;      // t-group 0..3
    const int hwl  = lane >> 2;     // tile pixel 0..15
    const int t0   = tg * 4;        // owns t0..t0+3
    const int h0   = (blockIdx.x >> 4) << 2;   // 16x16 tiles of 4x4
    const int w0   = (blockIdx.x & 15) << 2;

    // ---- stage all 18 channels of the 10x10x16 halo (edge-clamped; OOB
    //      pairs masked later by inb, same semantics as clamped loads) ----
#pragma unroll
    for (int rep = 0; rep < 4; ++rep) {
        const int q = tid + rep * 512;
        if (q < HWH * TT) {
            const int t   = q & 15;
            const int hwq = q >> 4;                  // 0..99
            const int hq  = (hwq * 205) >> 11;       // exact /10 for hwq<1024
            const int wq  = hwq - hq * 10;
            const int hs  = min(max(h0 - 3 + hq, 0), HH - 1);
            const int ws  = min(max(w0 - 3 + wq, 0), WW - 1);
            const int g   = (((hs << 6) + ws) << 4) + t;
            const int p   = SWZ(hwq, t);             // swizzled LDS address
#pragma unroll
            for (int c = 0; c < 9; ++c) smem[c * CH_SZ + p] = gui[c * NPIX + g];
#pragma unroll
            for (int c = 0; c < 3; ++c) {
                smem[(9 + c)  * CH_SZ + p] = est[c * NPIX + g];
                smem[(12 + c) * CH_SZ + p] = var[c * NPIX + g];
                smem[(15 + c) * CH_SZ + p] = img[c * NPIX + g];
            }
        }
    }
    __syncthreads();

    const int th = hwl >> 2, tw = hwl & 3;     // tile-local pixel
    const int hg = h0 + th,  wg = w0 + tw;     // global pixel

    // center values from LDS (float4 along t; slot-XOR preserves contiguity)
    const int rowc = (th + 3) * 10 + (tw + 3);
    const int lc = SWZ(rowc, t0);
    float4 sgc[9];                  // PRE-SCALED center guidance: sqrt(sig)*g
#pragma unroll
    for (int c = 0; c < 9; ++c) {
        float4 g4 = *(const float4*)&smem[c * CH_SZ + lc];
        sgc[c] = make_float4(g4.x * SQS[c], g4.y * SQS[c], g4.z * SQS[c], g4.w * SQS[c]);
    }
    float4 ec[3], vc[3];
#pragma unroll
    for (int c = 0; c < 3; ++c) {
        ec[c] = *(const float4*)&smem[(9 + c)  * CH_SZ + lc];
        vc[c] = *(const float4*)&smem[(12 + c) * CH_SZ + lc];
    }
    // hoisted column-invariant zero-tests (pure CSE; bit-identical semantics)
    bool vzc[3][4];
#pragma unroll
    for (int c = 0; c < 3; ++c) {
        vzc[c][0] = (vc[c].x == 0.f); vzc[c][1] = (vc[c].y == 0.f);
        vzc[c][2] = (vc[c].z == 0.f); vzc[c][3] = (vc[c].w == 0.f);
    }

    const bool vLo = (t0 != 0);     // pair (e=0,k=0): t0-1  (also DPP garbage mask)
    const bool vHi = (t0 != 12);    // pair (e=3,k=2): t0+4  (also DPP garbage mask)

    float acc[4][4] = {};   // per owned t: {r,g,b,wsum}

    int dh = s / 7 - 3, dw = s % 7 - 3;   // column r = s, then += 8
    for (int r = s; r < 49; r += 8) {
        // halo coords always in range: th+dh+3 in [0,9], tw+dw+3 in [0,9]
        const int rowb = rowc + dh * 10 + dw;
        const int lb   = SWZ(rowb, t0);
        const bool inb = ((unsigned)(hg + dh) < (unsigned)HH) &
                         ((unsigned)(wg + dw) < (unsigned)WW);

        // ---- bilateral over 9 guidance channels, 12 (e,dt) pairs ----
        float sb[4][3] = {};
#pragma unroll
        for (int c = 0; c < 9; ++c) {
            float4 m = *(const float4*)&smem[c * CH_SZ + lb];
            float4 sm = make_float4(m.x * SQS[c], m.y * SQS[c], m.z * SQS[c], m.w * SQS[c]);
            float nv[6] = {dpp_up1(sm.w), sm.x, sm.y, sm.z, sm.w, dpp_dn1(sm.x)};
            float ce[4] = {sgc[c].x, sgc[c].y, sgc[c].z, sgc[c].w};
#pragma unroll
            for (int e = 0; e < 4; ++e) {
#pragma unroll
                for (int k = 0; k < 3; ++k) {        // neighbor t = t0+e+k-1
                    float d = ce[e] - nv[e + k];
                    sb[e][k] = fmaf(d, d, sb[e][k]);
                }
            }
        }

        // ---- membership (division-free Welch t-test) ----
        // (OOB h/w neighbors provably get weight 0 in the reference -> inb;
        //  center pair passes naturally: d2==0.)
        bool mem[4][3] = {{1,1,1},{1,1,1},{1,1,1},{1,1,1}};
#pragma unroll
        for (int c = 0; c < 3; ++c) {
            float4 em = *(const float4*)&smem[(9 + c)  * CH_SZ + lb];
            float4 vm = *(const float4*)&smem[(12 + c) * CH_SZ + lb];
            float env[6] = {dpp_up1(em.w), em.x, em.y, em.z, em.w, dpp_dn1(em.x)};
            float vnv[6] = {dpp_up1(vm.w), vm.x, vm.y, vm.z, vm.w, dpp_dn1(vm.x)};
            bool  vzn[6];
#pragma unroll
            for (int j = 0; j < 6; ++j) vzn[j] = (vnv[j] == 0.f);
            float ece[4] = {ec[c].x, ec[c].y, ec[c].z, ec[c].w};
            float vce[4] = {vc[c].x, vc[c].y, vc[c].z, vc[c].w};
#pragma unroll
            for (int e = 0; e < 4; ++e) {
#pragma unroll
                for (int k = 0; k < 3; ++k) {
                    float d  = ece[e] - env[e + k];
                    float d2 = d * d;
                    float V  = vce[e] + vnv[e + k];
                    bool pass = (d2 < G2 * V) | ((d2 == 0.f) & (V == 0.f));
                    bool kill = (vzc[c][e] | vzn[e + k]) & (d2 != 0.f);
                    mem[e][k] = mem[e][k] & pass & (!kill);
                }
            }
        }

        // ---- weights ----
        float wt[4][3];
#pragma unroll
        for (int e = 0; e < 4; ++e) {
#pragma unroll
            for (int k = 0; k < 3; ++k) {
                bool ok = inb && mem[e][k];
                if (e == 0 && k == 0) ok = ok && vLo;   // t0-1
                if (e == 3 && k == 2) ok = ok && vHi;   // t0+4
                wt[e][k] = ok ? __expf(-0.5f * sb[e][k]) : 0.f;
            }
        }

        // ---- accumulate image (from LDS) ----
#pragma unroll
        for (int c = 0; c < 3; ++c) {
            float4 im = *(const float4*)&smem[(15 + c) * CH_SZ + lb];
            float iv[6] = {dpp_up1(im.w), im.x, im.y, im.z, im.w, dpp_dn1(im.x)};
#pragma unroll
            for (int e = 0; e < 4; ++e) {
                acc[e][c] = fmaf(wt[e][0], iv[e],
                            fmaf(wt[e][1], iv[e + 1],
                            fmaf(wt[e][2], iv[e + 2], acc[e][c])));
            }
        }
#pragma unroll
        for (int e = 0; e < 4; ++e)
            acc[e][3] += wt[e][0] + wt[e][1] + wt[e][2];

        dw += 8;
        while (dw > 3) { dw -= 7; ++dh; }
    }

    // ---- combine the 8 splits (alias staging LDS after all reads done) ----
    __syncthreads();
    float4* red = (float4*)smem;          // 8*64*4 float4 = 32 KB < 115.2 KB
#pragma unroll
    for (int e = 0; e < 4; ++e)
        red[(s * 64 + lane) * 4 + e] = make_float4(acc[e][0], acc[e][1], acc[e][2], acc[e][3]);
    __syncthreads();

    if (tid < 256) {
        const int hw_ = tid >> 4;           // tile pixel 0..15
        const int t_  = tid & 15;           // t 0..15
        const int tg_ = t_ >> 2, e_ = t_ & 3;
        const int li  = hw_ * 4 + tg_;      // lane that owns this (hw, t0) group
        float4 sum = make_float4(0.f, 0.f, 0.f, 0.f);
#pragma unroll
        for (int q = 0; q < 8; ++q) {
            float4 v = red[(q * 64 + li) * 4 + e_];
            sum.x += v.x; sum.y += v.y; sum.z += v.z; sum.w += v.w;
        }
        const int th_ = hw_ >> 2, tw_ = hw_ & 3;
        const int px = ((((h0 + th_) << 6) + (w0 + tw_)) << 4) + t_;
        const float inv = 1.f / sum.w;      // wsum >= 1 (center weight == 1)
        out[0 * NPIX + px] = sum.x * inv;
        out[1 * NPIX + px] = sum.y * inv;
        out[2 * NPIX + px] = sum.z * inv;
    }
}

extern "C" void kernel_launch(void* const* d_in, const int* in_sizes, int n_in,
                              void* d_out, int out_size, void* d_ws, size_t ws_size,
                              hipStream_t stream) {
    const float* img = (const float*)d_in[0];
    const float* gui = (const float*)d_in[1];
    const float* est = (const float*)d_in[2];
    const float* var = (const float*)d_in[3];
    float* out = (float*)d_out;

    dim3 grid(256);     // 16x16 tiles of 4x4x16, 1 block per CU (LDS-enforced)
    dim3 block(512);    // 8 waves = 8 column-splits; wave covers whole tile
    statdenoise_kernel<<<grid, block, 0, stream>>>(img, gui, est, var, out);
}